// Round 3
// baseline (495.593 us; speedup 1.0000x reference)
//
#include <hip/hip_runtime.h>
#include <hip/hip_bf16.h>
#include <stdint.h>

// Problem constants (from reference)
#define M_DIM 8192              // 4*2048 batch*seq rows
#define N_DIM 4096              // out_features
#define K_DIM 4096              // in_features
#define NOG   4096              // num out groups (out_group=1)
#define NIG   512               // num in groups (in_group=8)

typedef __bf16 bf16;
typedef __attribute__((ext_vector_type(8))) __bf16 bf16x8;   // 4 VGPRs — MFMA A/B frag
typedef __attribute__((ext_vector_type(4))) float f32x4;     // MFMA C/D frag

// Tiled bf16 layout for both GEMM operands ("chunk order"):
//   tile(g, h) = rows [g*16,(g+1)*16) x cols [h*32,(h+1)*32)
//   stored as 64 consecutive 16-B chunks, chunk index c = kblk*16 + row.
//   tile base (in chunks) = (g * (K_DIM/32) + h) * 64.
// GEMM staging reads 1024 CONTIGUOUS global bytes per gload16 (lane l ->
// chunk l) and LDS receives fragment-read order -> zero bank conflicts.

// ---------------------------------------------------------------------------
// async global->LDS, 16 B per lane. LDS dest is wave-uniform base + lane*16.
__device__ __forceinline__ void gload16(const void* g, void* lds) {
    __builtin_amdgcn_global_load_lds(
        (__attribute__((address_space(1))) void*)g,
        (__attribute__((address_space(3))) void*)lds,
        16 /*size*/, 0 /*offset*/, 0 /*aux*/);
}

// ---------------------------------------------------------------------------
// Kernel 1: fp32 -> bf16 convert + transpose into chunk-order tiles. (unchanged)
__global__ __launch_bounds__(256) void k_convert_tile(const float* __restrict__ in,
                                                      bf16* __restrict__ out) {
    __shared__ __align__(16) bf16 tile[256 * 8];   // 4 KB = 256 chunks
    const int t   = threadIdx.x;
    const int g   = blockIdx.y;          // row group (16 rows)
    const int h0  = blockIdx.x * 4;      // first 32-col half of the 4 we cover
    const int row = t >> 4;
    const int cc  = t & 15;              // 8-elem column chunk within 128 cols
    const float4* p = (const float4*)(in + (size_t)(g * 16 + row) * K_DIM
                                         + h0 * 32 + cc * 8);
    float4 a = p[0], b = p[1];
    bf16x8 v;
    v[0] = (bf16)a.x; v[1] = (bf16)a.y; v[2] = (bf16)a.z; v[3] = (bf16)a.w;
    v[4] = (bf16)b.x; v[5] = (bf16)b.y; v[6] = (bf16)b.z; v[7] = (bf16)b.w;
    const int widx = (cc >> 2) * 64 + (cc & 3) * 16 + row;
    ((bf16x8*)tile)[widx] = v;
    __syncthreads();
    bf16x8 o = ((bf16x8*)tile)[t];
    ((bf16x8*)out)[((size_t)g * 128 + h0) * 64 + t] = o;   // contiguous 4 KB store
}

// ---------------------------------------------------------------------------
// Kernel 2: AQLM dequant straight into chunk-order tiles. (unchanged)
__global__ __launch_bounds__(256) void k_dequant_tile(const int* __restrict__ codes,
                                                      const float* __restrict__ cb,
                                                      const float* __restrict__ scales,
                                                      bf16* __restrict__ w) {
    const int t    = threadIdx.x;
    const int gB   = blockIdx.y;           // out-feature group (16 rows)
    const int h0   = blockIdx.x * 4;       // first 32-col half
    const int hl   = t >> 6;               // half within block (0..3)
    const int kblk = (t >> 4) & 3;         // in-group within half
    const int row  = t & 15;               // out-feature within group
    const int o    = gB * 16 + row;
    const int iG   = blockIdx.x * 16 + hl * 4 + kblk;
    unsigned code = (unsigned)codes[o * NIG + iG];
    float s = scales[o];
    const float4* e = (const float4*)(cb + (size_t)code * 8);
    float4 e0 = e[0], e1 = e[1];
    bf16x8 v;
    v[0] = (bf16)(e0.x * s); v[1] = (bf16)(e0.y * s);
    v[2] = (bf16)(e0.z * s); v[3] = (bf16)(e0.w * s);
    v[4] = (bf16)(e1.x * s); v[5] = (bf16)(e1.y * s);
    v[6] = (bf16)(e1.z * s); v[7] = (bf16)(e1.w * s);
    ((bf16x8*)w)[((size_t)gB * 128 + h0) * 64 + t] = v;
}

// ---------------------------------------------------------------------------
// Kernel 3: C[m,n] = sum_k A[m,k]*B[n,k] + bias[n]  on chunk-order tiles.
//
// Pipelined schedule: BM=BN=256, 8 waves (2M x 4N), wave tile 128x64.
// 128 k-slices (32 wide). LDS = ring of 4 slice-slots (32 KB each: A 16 KB
// + B 16 KB). Per phase s (one slice):
//   1. ds_read 12 frags of slice s+1 -> frag bank (s+1)&1   [reads overlap
//      THIS phase's MFMAs -> removes the read->MFMA serialization that
//      capped round 2 at MfmaUtil 49%]
//   2. 4 gload16 staging slice s+3 -> ring slot (s+3)&3
//   3. s_waitcnt lgkmcnt(12): slice s's frags ready, s+1's still in flight
//   4. sched_barrier(0) (rule 18: MFMAs must not hoist above the wait)
//   5. setprio(1) 32x MFMA on bank s&1 setprio(0)
//   6. s_waitcnt vmcnt(4): drains slice s+2's staging (read next phase);
//      slice s+3's 4 loads stay in flight  [counted, never 0 in loop]
//   7. s_barrier + sched_barrier(0) (cross-wave visibility of s+2; fences
//      the next phase's ds_reads/gloads; preserves in-order DS counting)
// Hazards:
//  - read(s+1) at phase s: staged phase s-2, drained by phase s-1's
//    vmcnt(4), made visible by phase s-1's barrier.  OK
//  - gload(s+3) overwrites slot of slice s-1: all waves' reads of s-1
//    completed at phase s-1's lgkmcnt(12), before phase s-1's barrier,
//    before these gloads issue.  OK
//  - frag banks ping-pong with STATIC names via 4x unroll (rule 20).
#define BM 256
#define BN 256
#define NSLICE (K_DIM / 32)     // 128

__device__ __forceinline__ void ds_read_frags(
    const bf16* slot, int gA0, int gB0, int lane,
    bf16x8 (&af)[8], bf16x8 (&bq)[4])
{
    #pragma unroll
    for (int m = 0; m < 8; ++m)
        af[m] = *(const bf16x8*)(slot + (gA0 + m) * 512 + lane * 8);
    #pragma unroll
    for (int j = 0; j < 4; ++j)
        bq[j] = *(const bf16x8*)(slot + 8192 + (gB0 + j) * 512 + lane * 8);
}

__device__ __forceinline__ void stage_slice(
    bf16* slot, const bf16* pa0, const bf16* pa1,
    const bf16* pb0, const bf16* pb1, int w2, int ss)
{
    const size_t off = (size_t)ss * 512;
    gload16(pa0 + off, slot + (w2 + 0) * 512);          // A group w2
    gload16(pa1 + off, slot + (w2 + 1) * 512);          // A group w2+1
    gload16(pb0 + off, slot + 8192 + (w2 + 0) * 512);   // B group w2
    gload16(pb1 + off, slot + 8192 + (w2 + 1) * 512);   // B group w2+1
}

__device__ __forceinline__ void mfma_cluster(
    const bf16x8 (&af)[8], const bf16x8 (&bq)[4], f32x4 (&acc)[8][4])
{
    __builtin_amdgcn_s_setprio(1);
    #pragma unroll
    for (int i = 0; i < 8; ++i)
        #pragma unroll
        for (int j = 0; j < 4; ++j)
            acc[i][j] = __builtin_amdgcn_mfma_f32_16x16x32_bf16(
                af[i], bq[j], acc[i][j], 0, 0, 0);
    __builtin_amdgcn_s_setprio(0);
}

__global__ __launch_bounds__(512, 2) void k_gemm_tiled(
    const bf16* __restrict__ A,      // chunk-order tiled [512 groups][128 halves]
    const bf16* __restrict__ B,      // chunk-order tiled [256 groups][128 halves]
    const float* __restrict__ bias,  // [N_DIM]
    float* __restrict__ C)           // [M_DIM, N_DIM] row-major
{
    __shared__ __align__(16) bf16 ring[4][16384];   // 4 x 32 KB = 128 KB

    const int tid  = threadIdx.x;
    const int wave = tid >> 6;         // 0..7
    const int lane = tid & 63;
    const int quad = lane >> 4;        // 0..3
    const int l16  = lane & 15;
    const int w2   = wave * 2;

    // XCD-aware bijective remap (T1): 512 blocks, 512%8==0. hw order is
    // x-fastest; give each XCD a contiguous run of 4 M-rows of tiles so its
    // L2 holds a small A slice + the shared B panel.
    const int bhw = blockIdx.y * 16 + blockIdx.x;
    const int bsz = (bhw & 7) * 64 + (bhw >> 3);
    const int bx  = bsz & 15;          // logical N tile
    const int by  = bsz >> 4;          // logical M tile

    const int bn0 = bx * BN;
    const int bm0 = by * BM;
    const int wm  = (wave >> 2) * 128; // wave's 128x64 subtile
    const int wn  = (wave & 3) * 64;
    const int gA0 = (wave >> 2) * 8;   // first A group this wave's frags use
    const int gB0 = (wave & 3) * 4;    // first B group

    // Staging sources: wave w stages A groups {2w,2w+1}, B groups {2w,2w+1};
    // lane l fetches chunk l. Group stride = 8192 chunks (*8 elems).
    const bf16* pa0 = A + ((size_t)(by * 16 + w2 + 0) * 8192 + lane) * 8;
    const bf16* pa1 = A + ((size_t)(by * 16 + w2 + 1) * 8192 + lane) * 8;
    const bf16* pb0 = B + ((size_t)(bx * 16 + w2 + 0) * 8192 + lane) * 8;
    const bf16* pb1 = B + ((size_t)(bx * 16 + w2 + 1) * 8192 + lane) * 8;

    f32x4 acc[8][4] = {};
    bf16x8 afA[8], bqA[4], afB[8], bqB[4];   // ping-pong frag banks

    // Prologue: stage slices 0,1,2 into slots 0,1,2; drain 0,1; read frags(0).
    stage_slice(&ring[0][0], pa0, pa1, pb0, pb1, w2, 0);
    stage_slice(&ring[1][0], pa0, pa1, pb0, pb1, w2, 1);
    stage_slice(&ring[2][0], pa0, pa1, pb0, pb1, w2, 2);
    asm volatile("s_waitcnt vmcnt(4)" ::: "memory");   // slices 0,1 landed
    __builtin_amdgcn_s_barrier();
    __builtin_amdgcn_sched_barrier(0);
    ds_read_frags(&ring[0][0], gA0, gB0, lane, afA, bqA);   // frags(0) -> bank A
    __builtin_amdgcn_sched_barrier(0);   // keep issue order vs phase-0 reads

// One pipeline phase. RD: ring slot of slice s+1. ST: ring slot of slice
// s+3. SS: s+3. C/N: current/next frag banks.
#define PHASE(RD, ST, SS, AFC, BQC, AFN, BQN)                                \
    ds_read_frags(&ring[RD][0], gA0, gB0, lane, AFN, BQN);                   \
    stage_slice(&ring[ST][0], pa0, pa1, pb0, pb1, w2, (SS));                 \
    asm volatile("s_waitcnt lgkmcnt(12)" ::: "memory");                      \
    __builtin_amdgcn_sched_barrier(0);                                       \
    mfma_cluster(AFC, BQC, acc);                                             \
    asm volatile("s_waitcnt vmcnt(4)" ::: "memory");                         \
    __builtin_amdgcn_s_barrier();                                            \
    __builtin_amdgcn_sched_barrier(0);

    for (int t = 0; t < 31; ++t) {       // phases 0..123 (s = 4t+i)
        const int s0 = t * 4;
        PHASE(1, 3, s0 + 3, afA, bqA, afB, bqB);   // s=4t
        PHASE(2, 0, s0 + 4, afB, bqB, afA, bqA);   // s=4t+1
        PHASE(3, 1, s0 + 5, afA, bqA, afB, bqB);   // s=4t+2
        PHASE(0, 2, s0 + 6, afB, bqB, afA, bqA);   // s=4t+3
    }

    // Tail: phases 124..127 (no staging past slice 127).
    // phase 124: stage ss=127 -> slot 3; read frags(125) slot 1; MFMA bank A.
    ds_read_frags(&ring[1][0], gA0, gB0, lane, afB, bqB);
    stage_slice(&ring[3][0], pa0, pa1, pb0, pb1, w2, 127);
    asm volatile("s_waitcnt lgkmcnt(12)" ::: "memory");
    __builtin_amdgcn_sched_barrier(0);
    mfma_cluster(afA, bqA, acc);
    asm volatile("s_waitcnt vmcnt(4)" ::: "memory");   // slice 126 landed
    __builtin_amdgcn_s_barrier();
    __builtin_amdgcn_sched_barrier(0);
    // phase 125: read frags(126) slot 2; MFMA bank B.
    ds_read_frags(&ring[2][0], gA0, gB0, lane, afA, bqA);
    asm volatile("s_waitcnt lgkmcnt(12)" ::: "memory");
    __builtin_amdgcn_sched_barrier(0);
    mfma_cluster(afB, bqB, acc);
    asm volatile("s_waitcnt vmcnt(0)" ::: "memory");   // slice 127 landed
    __builtin_amdgcn_s_barrier();
    __builtin_amdgcn_sched_barrier(0);
    // phase 126: read frags(127) slot 3; MFMA bank A.
    ds_read_frags(&ring[3][0], gA0, gB0, lane, afB, bqB);
    asm volatile("s_waitcnt lgkmcnt(12)" ::: "memory");
    __builtin_amdgcn_sched_barrier(0);
    mfma_cluster(afA, bqA, acc);
    // phase 127: MFMA bank B.
    asm volatile("s_waitcnt lgkmcnt(0)" ::: "memory");
    __builtin_amdgcn_sched_barrier(0);
    mfma_cluster(afB, bqB, acc);
#undef PHASE

    // Epilogue: C/D layout col = lane&15, row = quad*4 + reg  [m89/m91-verified]
    #pragma unroll
    for (int j = 0; j < 4; ++j) {
        const int gn = bn0 + wn + j * 16 + l16;
        const float bz = bias[gn];
        #pragma unroll
        for (int i = 0; i < 8; ++i) {
            float* cp = C + (size_t)(bm0 + wm + i * 16 + quad * 4) * N_DIM + gn;
            #pragma unroll
            for (int r = 0; r < 4; ++r)
                cp[(size_t)r * N_DIM] = acc[i][j][r] + bz;
        }
    }
}

// ---------------------------------------------------------------------------
extern "C" void kernel_launch(void* const* d_in, const int* in_sizes, int n_in,
                              void* d_out, int out_size, void* d_ws, size_t ws_size,
                              hipStream_t stream) {
    const float* input     = (const float*)d_in[0];   // [4,2048,4096]
    const int*   codes     = (const int*)d_in[1];     // [4096,512,1]
    const float* codebooks = (const float*)d_in[2];   // [1,65536,1,8]
    const float* scales    = (const float*)d_in[3];   // [4096]
    const float* bias      = (const float*)d_in[4];   // [4096]
    float* out = (float*)d_out;                        // [4,2048,4096]

    // Workspace: A_tiled (67.1 MB) then W_tiled (33.5 MB); both fully written
    // before the GEMM reads them, so the 0xAA poison is irrelevant.
    bf16* Abf = (bf16*)d_ws;
    bf16* Wbf = (bf16*)((char*)d_ws + (size_t)M_DIM * K_DIM * sizeof(bf16));

    (void)in_sizes; (void)n_in; (void)out_size; (void)ws_size;

    // 1) activation fp32 -> bf16, tiled  (grid: 32 col-quads x 512 row-groups)
    {
        dim3 g(K_DIM / 128, M_DIM / 16);
        k_convert_tile<<<g, 256, 0, stream>>>(input, Abf);
    }
    // 2) dequantize W -> bf16, tiled  (grid: 32 col-quads x 256 row-groups)
    {
        dim3 g(K_DIM / 128, NOG / 16);
        k_dequant_tile<<<g, 256, 0, stream>>>(codes, codebooks, scales, Wbf);
    }
    // 3) NT GEMM + bias, ring-pipelined schedule
    {
        dim3 g(N_DIM / BN, M_DIM / BM);   // (16, 32) = 512 blocks
        k_gemm_tiled<<<g, 512, 0, stream>>>(Abf, Wbf, bias, out);
    }
}

// Round 4
// 460.448 us; speedup vs baseline: 1.0763x; 1.0763x over previous
//
#include <hip/hip_runtime.h>
#include <hip/hip_bf16.h>
#include <stdint.h>

// Problem constants (from reference)
#define M_DIM 8192              // 4*2048 batch*seq rows
#define N_DIM 4096              // out_features
#define K_DIM 4096              // in_features
#define NOG   4096              // num out groups (out_group=1)
#define NIG   512               // num in groups (in_group=8)

typedef __bf16 bf16;
typedef __attribute__((ext_vector_type(8))) __bf16 bf16x8;   // 4 VGPRs — MFMA A/B frag
typedef __attribute__((ext_vector_type(4))) float f32x4;     // MFMA C/D frag

// Tiled bf16 layout for both GEMM operands ("chunk order"):
//   tile(g, h) = rows [g*16,(g+1)*16) x cols [h*32,(h+1)*32)
//   stored as 64 consecutive 16-B chunks, chunk index c = kblk*16 + row.
//   tile base (in chunks) = (g * (K_DIM/32) + h) * 64.
// GEMM staging reads 1024 CONTIGUOUS global bytes per gload16 (lane l ->
// chunk l) and LDS receives fragment-read order -> zero bank conflicts.

// ---------------------------------------------------------------------------
// async global->LDS, 16 B per lane. LDS dest is wave-uniform base + lane*16.
__device__ __forceinline__ void gload16(const void* g, void* lds) {
    __builtin_amdgcn_global_load_lds(
        (__attribute__((address_space(1))) void*)g,
        (__attribute__((address_space(3))) void*)lds,
        16 /*size*/, 0 /*offset*/, 0 /*aux*/);
}

// ---------------------------------------------------------------------------
// Kernel 1: fp32 -> bf16 convert + transpose into chunk-order tiles.
// LDS chunk index is XOR-swizzled on BOTH sides: the natural layout put
// bank = f(row) only -> 16-way ds_write_b128 conflict. phys(i) spreads each
// 8-lane group across all 8 bank-quads on write AND read (even -> free).
__device__ __forceinline__ int chunk_swz(int i) {
    return i ^ (((i >> 3) ^ (i >> 6)) & 7);
}

__global__ __launch_bounds__(256) void k_convert_tile(const float* __restrict__ in,
                                                      bf16* __restrict__ out) {
    __shared__ __align__(16) bf16 tile[256 * 8];   // 4 KB = 256 chunks
    const int t   = threadIdx.x;
    const int g   = blockIdx.y;          // row group (16 rows)
    const int h0  = blockIdx.x * 4;      // first 32-col half of the 4 we cover
    const int row = t >> 4;
    const int cc  = t & 15;              // 8-elem column chunk within 128 cols
    const float4* p = (const float4*)(in + (size_t)(g * 16 + row) * K_DIM
                                         + h0 * 32 + cc * 8);
    float4 a = p[0], b = p[1];
    bf16x8 v;
    v[0] = (bf16)a.x; v[1] = (bf16)a.y; v[2] = (bf16)a.z; v[3] = (bf16)a.w;
    v[4] = (bf16)b.x; v[5] = (bf16)b.y; v[6] = (bf16)b.z; v[7] = (bf16)b.w;
    const int widx = (cc >> 2) * 64 + (cc & 3) * 16 + row;
    ((bf16x8*)tile)[chunk_swz(widx)] = v;
    __syncthreads();
    bf16x8 o = ((bf16x8*)tile)[chunk_swz(t)];
    ((bf16x8*)out)[((size_t)g * 128 + h0) * 64 + t] = o;   // contiguous 4 KB store
}

// ---------------------------------------------------------------------------
// Kernel 2: AQLM dequant straight into chunk-order tiles. (unchanged)
__global__ __launch_bounds__(256) void k_dequant_tile(const int* __restrict__ codes,
                                                      const float* __restrict__ cb,
                                                      const float* __restrict__ scales,
                                                      bf16* __restrict__ w) {
    const int t    = threadIdx.x;
    const int gB   = blockIdx.y;           // out-feature group (16 rows)
    const int h0   = blockIdx.x * 4;       // first 32-col half
    const int hl   = t >> 6;               // half within block (0..3)
    const int kblk = (t >> 4) & 3;         // in-group within half
    const int row  = t & 15;               // out-feature within group
    const int o    = gB * 16 + row;
    const int iG   = blockIdx.x * 16 + hl * 4 + kblk;
    unsigned code = (unsigned)codes[o * NIG + iG];
    float s = scales[o];
    const float4* e = (const float4*)(cb + (size_t)code * 8);
    float4 e0 = e[0], e1 = e[1];
    bf16x8 v;
    v[0] = (bf16)(e0.x * s); v[1] = (bf16)(e0.y * s);
    v[2] = (bf16)(e0.z * s); v[3] = (bf16)(e0.w * s);
    v[4] = (bf16)(e1.x * s); v[5] = (bf16)(e1.y * s);
    v[6] = (bf16)(e1.z * s); v[7] = (bf16)(e1.w * s);
    ((bf16x8*)w)[((size_t)gB * 128 + h0) * 64 + t] = v;
}

// ---------------------------------------------------------------------------
// Kernel 3: C[m,n] = sum_k A[m,k]*B[n,k] + bias[n]  — m201 8-phase template.
//
// BM=BN=256, BK=64 (one K-tile = 2 32-wide sub-slices kk), 8 waves (2M x 4N),
// wave tile 128x64. LDS: AL/BL[buf][half][8 groups x 1024] = 128 KB total.
// Even K-tiles live in buf0, odd in buf1 (no pointer swap).
//
// Per-wave frag sources are FIXED halves: halfA = wave>>2 (its 128 rows),
// halfB = (wave&3)>>1 (its 64 cols); slotB0 = (wave&1)*4.
//
// 8 phases per iteration (2 K-tiles kt=2t [buf0] and kt+1 [buf1]); phase =
//   { ds_read this phase's quadrant frags | stage ONE half-tile (2 gload16)
//     | vmcnt(4) | barrier | lgkmcnt(0)+sched_barrier | setprio(1) 16 MFMA
//     setprio(0) | barrier }
// Quadrant order per K-tile: (mh0,nh0)(mh0,nh1)(mh1,nh1)(mh1,nh0) — B frags
// for both nh are held live (bqA/bqB), A frags ping-pong (afA/afB): reads
// per K-tile = 24 b128 (minimum).
//
// Staging schedule (each phase stages one half-tile; all waves stage their
// own group-slot w of that half):
//   p1: A-h0(2t+1)->buf1   p2: A-h1(2t+1)->buf1
//   p3: B-h0(2t+2)->buf0   p4: B-h1(2t+2)->buf0
//   p5: A-h0(2t+2)->buf0   p6: A-h1(2t+2)->buf0
//   p7: B-h0(2t+3)->buf1   p8: B-h1(2t+3)->buf1
// Overwrite-after-consume: buf0 B-halves consumed p1,p2 (staged p3,p4 after
// p2's end-barrier); buf0 A-halves consumed p1,p3 (staged p5,p6); buf1 B
// consumed p5,p6 (staged p7,p8); buf1 A consumed p5,p7 (staged next p1,p2).
// Read-after-stage: vmcnt(4) after each phase's stage leaves {this,prev}
// half-tiles in flight => stage(p-3) landed before phase p's reads (gated by
// p-1's vmcnt+barrier). Tightest: A-h1(2t+1)@p2 read @p5 (gate p4 drains p2),
// A-h1(2t+2)@p6 read @next p1 (gate p8 drains p6). All exact-covered.
// Tail: stages with kt >= 64 skipped (wave-uniform; vmcnt still satisfiable).
#define BM 256
#define BN 256
#define KTILES (K_DIM / 64)     // 64

__global__ __launch_bounds__(512, 2) void k_gemm_tiled(
    const bf16* __restrict__ A,      // chunk-order tiled [512 groups][128 halves]
    const bf16* __restrict__ B,      // chunk-order tiled [256 groups][128 halves]
    const float* __restrict__ bias,  // [N_DIM]
    float* __restrict__ C)           // [M_DIM, N_DIM] row-major
{
    __shared__ __align__(16) bf16 AL[2][2][8192];   // [buf][half][8g x 1024] 64 KB
    __shared__ __align__(16) bf16 BL[2][2][8192];   // 64 KB

    const int tid  = threadIdx.x;
    const int wave = tid >> 6;         // 0..7
    const int lane = tid & 63;
    const int quad = lane >> 4;        // 0..3
    const int l16  = lane & 15;

    // XCD-aware bijective remap (T1): 512 blocks, 512%8==0.
    const int bhw = blockIdx.y * 16 + blockIdx.x;
    const int bsz = (bhw & 7) * 64 + (bhw >> 3);
    const int bx  = bsz & 15;          // logical N tile
    const int by  = bsz >> 4;          // logical M tile

    const int bn0 = bx * BN;
    const int bm0 = by * BM;
    const int wm  = (wave >> 2) * 128; // wave's 128x64 subtile
    const int wn  = (wave & 3) * 64;

    const int halfA = wave >> 2;           // fixed A half this wave reads
    const int halfB = (wave & 3) >> 1;     // fixed B half
    const int bslot = (wave & 1) * 4;      // first B group-slot within half

    // Staging sources: wave w stages group-slot w of each half.
    const bf16* gA0 = A + ((size_t)(by * 16 + wave)      * 8192 + lane) * 8;
    const bf16* gA1 = A + ((size_t)(by * 16 + 8 + wave)  * 8192 + lane) * 8;
    const bf16* gB0 = B + ((size_t)(bx * 16 + wave)      * 8192 + lane) * 8;
    const bf16* gB1 = B + ((size_t)(bx * 16 + 8 + wave)  * 8192 + lane) * 8;

    f32x4 acc[8][4] = {};
    bf16x8 afA[8], afB[8], bqA[4], bqB[4];

// ---- building blocks -------------------------------------------------------
#define STAGE_A(buf, half, kt) do { if ((kt) < KTILES) {                      \
        const bf16* s_ = ((half) ? gA1 : gA0) + (size_t)(kt) * 1024;          \
        bf16* d_ = &AL[buf][half][wave * 1024];                               \
        gload16(s_, d_); gload16(s_ + 512, d_ + 512); } } while (0)
#define STAGE_B(buf, half, kt) do { if ((kt) < KTILES) {                      \
        const bf16* s_ = ((half) ? gB1 : gB0) + (size_t)(kt) * 1024;          \
        bf16* d_ = &BL[buf][half][wave * 1024];                               \
        gload16(s_, d_); gload16(s_ + 512, d_ + 512); } } while (0)
#define READ_A(af, buf, mh) {                                                 \
    _Pragma("unroll") for (int i_ = 0; i_ < 4; ++i_)                          \
    _Pragma("unroll") for (int kk_ = 0; kk_ < 2; ++kk_)                       \
        af[i_ * 2 + kk_] = *(const bf16x8*)(&AL[buf][halfA]                   \
            [((mh) * 4 + i_) * 1024 + kk_ * 512 + lane * 8]); }
#define READ_B(bq, buf, nh) {                                                 \
    _Pragma("unroll") for (int j_ = 0; j_ < 2; ++j_)                          \
    _Pragma("unroll") for (int kk_ = 0; kk_ < 2; ++kk_)                       \
        bq[j_ * 2 + kk_] = *(const bf16x8*)(&BL[buf][halfB]                   \
            [(bslot + (nh) * 2 + j_) * 1024 + kk_ * 512 + lane * 8]); }
#define FENCE() do {                                                          \
        asm volatile("s_waitcnt vmcnt(4)" ::: "memory");                      \
        __builtin_amdgcn_s_barrier(); } while (0)
#define MFMA16(af, bq, mh, nh) do {                                           \
        asm volatile("s_waitcnt lgkmcnt(0)" ::: "memory");                    \
        __builtin_amdgcn_sched_barrier(0);                                    \
        __builtin_amdgcn_s_setprio(1);                                        \
        _Pragma("unroll") for (int kk_ = 0; kk_ < 2; ++kk_)                   \
        _Pragma("unroll") for (int i_ = 0; i_ < 4; ++i_)                      \
        _Pragma("unroll") for (int j_ = 0; j_ < 2; ++j_)                      \
            acc[(mh) * 4 + i_][(nh) * 2 + j_] =                               \
                __builtin_amdgcn_mfma_f32_16x16x32_bf16(                      \
                    af[i_ * 2 + kk_], bq[j_ * 2 + kk_],                       \
                    acc[(mh) * 4 + i_][(nh) * 2 + j_], 0, 0, 0);              \
        __builtin_amdgcn_s_setprio(0);                                        \
        __builtin_amdgcn_s_barrier(); } while (0)

    // Prologue: kt0 fully + kt1 B-halves; drain; barrier.
    STAGE_B(0, 0, 0); STAGE_B(0, 1, 0);
    STAGE_A(0, 0, 0); STAGE_A(0, 1, 0);
    STAGE_B(1, 0, 1); STAGE_B(1, 1, 1);
    asm volatile("s_waitcnt vmcnt(0)" ::: "memory");
    __builtin_amdgcn_s_barrier();

    for (int t = 0; t < KTILES / 2; ++t) {
        const int k1 = 2 * t + 1, k2 = 2 * t + 2, k3 = 2 * t + 3;
        // ---- K-tile 2t (buf0) ----
        READ_A(afA, 0, 0); READ_B(bqA, 0, 0);     // p1
        STAGE_A(1, 0, k1);
        FENCE(); MFMA16(afA, bqA, 0, 0);
        READ_B(bqB, 0, 1);                        // p2
        STAGE_A(1, 1, k1);
        FENCE(); MFMA16(afA, bqB, 0, 1);
        READ_A(afB, 0, 1);                        // p3
        STAGE_B(0, 0, k2);
        FENCE(); MFMA16(afB, bqB, 1, 1);
        STAGE_B(0, 1, k2);                        // p4
        FENCE(); MFMA16(afB, bqA, 1, 0);
        // ---- K-tile 2t+1 (buf1) ----
        READ_A(afA, 1, 0); READ_B(bqA, 1, 0);     // p5
        STAGE_A(0, 0, k2);
        FENCE(); MFMA16(afA, bqA, 0, 0);
        READ_B(bqB, 1, 1);                        // p6
        STAGE_A(0, 1, k2);
        FENCE(); MFMA16(afA, bqB, 0, 1);
        READ_A(afB, 1, 1);                        // p7
        STAGE_B(1, 0, k3);
        FENCE(); MFMA16(afB, bqB, 1, 1);
        STAGE_B(1, 1, k3);                        // p8
        FENCE(); MFMA16(afB, bqA, 1, 0);
    }
#undef STAGE_A
#undef STAGE_B
#undef READ_A
#undef READ_B
#undef FENCE
#undef MFMA16

    // Epilogue: C/D layout col = lane&15, row = quad*4 + reg  [m89/m91-verified]
    #pragma unroll
    for (int j = 0; j < 4; ++j) {
        const int gn = bn0 + wn + j * 16 + l16;
        const float bz = bias[gn];
        #pragma unroll
        for (int i = 0; i < 8; ++i) {
            float* cp = C + (size_t)(bm0 + wm + i * 16 + quad * 4) * N_DIM + gn;
            #pragma unroll
            for (int r = 0; r < 4; ++r)
                cp[(size_t)r * N_DIM] = acc[i][j][r] + bz;
        }
    }
}

// ---------------------------------------------------------------------------
extern "C" void kernel_launch(void* const* d_in, const int* in_sizes, int n_in,
                              void* d_out, int out_size, void* d_ws, size_t ws_size,
                              hipStream_t stream) {
    const float* input     = (const float*)d_in[0];   // [4,2048,4096]
    const int*   codes     = (const int*)d_in[1];     // [4096,512,1]
    const float* codebooks = (const float*)d_in[2];   // [1,65536,1,8]
    const float* scales    = (const float*)d_in[3];   // [4096]
    const float* bias      = (const float*)d_in[4];   // [4096]
    float* out = (float*)d_out;                        // [4,2048,4096]

    // Workspace: A_tiled (67.1 MB) then W_tiled (33.5 MB); both fully written
    // before the GEMM reads them, so the 0xAA poison is irrelevant.
    bf16* Abf = (bf16*)d_ws;
    bf16* Wbf = (bf16*)((char*)d_ws + (size_t)M_DIM * K_DIM * sizeof(bf16));

    (void)in_sizes; (void)n_in; (void)out_size; (void)ws_size;

    // 1) activation fp32 -> bf16, tiled  (grid: 32 col-quads x 512 row-groups)
    {
        dim3 g(K_DIM / 128, M_DIM / 16);
        k_convert_tile<<<g, 256, 0, stream>>>(input, Abf);
    }
    // 2) dequantize W -> bf16, tiled  (grid: 32 col-quads x 256 row-groups)
    {
        dim3 g(K_DIM / 128, NOG / 16);
        k_dequant_tile<<<g, 256, 0, stream>>>(codes, codebooks, scales, Wbf);
    }
    // 3) NT GEMM + bias, 8-phase schedule
    {
        dim3 g(N_DIM / BN, M_DIM / BM);   // (16, 32) = 512 blocks
        k_gemm_tiled<<<g, 512, 0, stream>>>(Abf, Wbf, bias, out);
    }
}